// Round 8
// baseline (106.634 us; speedup 1.0000x reference)
//
#include <hip/hip_runtime.h>

typedef __bf16 bf16x8 __attribute__((ext_vector_type(8)));
typedef __bf16 bf16x2 __attribute__((ext_vector_type(2)));
typedef float  f32x4  __attribute__((ext_vector_type(4)));

// ws layout (bytes). All A-operand fragments lane-linear:
// one frag = 1024 B; lane l's 16 B at frag_base + l*16 (coalesced dwordx4).
//   WT0 : 8 frags   (nt 0..7, K=32 zero-padded)      [0      .. 8191  ]
//   WTH : 160 frags ((h*4+ks)*8 + nt)                [8192   .. 172031]
//   WLT : 8 frags   (ks 0..3 real, 4..7 zero pad)    [172032 .. 180223]
#define WS_WT0_B 0
#define WS_WTH_B 8192
#define WS_WLT_B 172032

__device__ __forceinline__ unsigned short f2b(float f) {
  return __builtin_bit_cast(unsigned short, (__bf16)f);
}

__global__ void prep_kernel(const float* __restrict__ W0,
                            const float* __restrict__ Wh,
                            const float* __restrict__ WL,
                            unsigned short* __restrict__ ws) {
  int i = blockIdx.x * 256 + threadIdx.x;   // ushort index == byte/2
  int l  = (i >> 3) & 63;                   // lane within frag
  int j  = i & 7;                           // element within lane's 8
  int lm = l & 15, lh = l >> 4;
  if (i < 4096) {                           // WT0
    int nt = i >> 9;
    int n = nt * 16 + lm, k = lh * 8 + j;
    ws[i] = f2b(k < 4 ? W0[k * 128 + n] : 0.f);
  } else if (i < 86016) {                   // WTH
    int t = i - 4096;
    int frag = t >> 9;                      // (h*4+ks)*8 + nt
    int nt = frag & 7, ks = (frag >> 3) & 3, h = frag >> 5;
    int n = nt * 16 + lm, k = ks * 32 + lh * 8 + j;
    ws[i] = f2b(Wh[(h * 128 + k) * 128 + n]);
  } else if (i < 90112) {                   // WLT (8 frags, 4 real + 4 zero)
    int t = i - 86016;
    int f = t >> 9;
    int k = (f & 3) * 32 + lh * 8 + j;
    ws[i] = f2b((f < 4 && lm < 2) ? WL[k * 2 + lm] : 0.f);
  }
}

// swish with packed exp-arg: u = z * -log2(e) (v_pk_mul), e = 2^u (v_exp_f32),
// s = rcp(1+e), out = z*s.
__device__ __forceinline__ f32x4 swish4(f32x4 z) {
  const f32x4 u = z * (-1.44269504088896340736f);   // 2x v_pk_mul
  f32x4 e;
#if __has_builtin(__builtin_amdgcn_exp2f)
  e[0] = __builtin_amdgcn_exp2f(u[0]); e[1] = __builtin_amdgcn_exp2f(u[1]);
  e[2] = __builtin_amdgcn_exp2f(u[2]); e[3] = __builtin_amdgcn_exp2f(u[3]);
#else
  e[0] = __expf(u[0] * 0.6931471805599453f); e[1] = __expf(u[1] * 0.6931471805599453f);
  e[2] = __expf(u[2] * 0.6931471805599453f); e[3] = __expf(u[3] * 0.6931471805599453f);
#endif
  const f32x4 w = e + 1.f;                          // 2x v_pk_add
  f32x4 s;
  s[0] = __builtin_amdgcn_rcpf(w[0]); s[1] = __builtin_amdgcn_rcpf(w[1]);
  s[2] = __builtin_amdgcn_rcpf(w[2]); s[3] = __builtin_amdgcn_rcpf(w[3]);
  return z * s;                                     // 2x v_pk_mul
}

__device__ __forceinline__ uint2 pack4(f32x4 r) {   // v_cvt_pk_bf16_f32 path
  bf16x2 lo = {(__bf16)r[0], (__bf16)r[1]};
  bf16x2 hi = {(__bf16)r[2], (__bf16)r[3]};
  uint2 wv;
  wv.x = __builtin_bit_cast(unsigned int, lo);
  wv.y = __builtin_bit_cast(unsigned int, hi);
  return wv;
}

#define SB() __builtin_amdgcn_sched_barrier(0)
#define GLD(addr) __builtin_bit_cast(bf16x8, *reinterpret_cast<const uint4*>(addr))
#define LRD(addr) __builtin_bit_cast(bf16x8, *reinterpret_cast<const uint4*>(addr))
#define MFMA(a, b, c) __builtin_amdgcn_mfma_f32_16x16x32_bf16((a), (b), (c), 0, 0, 0)

// One wave per block; each wave owns 32 points through ALL layers. No barriers.
// 2-stage software pipeline on weight frags; sched_barrier(0) pins phases.
// Biases ride in as MFMA C operands (phase 0); next layer's bias prefetched
// right after the current one is consumed (single rotating register set).
__launch_bounds__(64, 3)
__global__ void mlp_kernel(const float* __restrict__ X,
                           const float* __restrict__ nu_min_p,
                           const float* __restrict__ nu_max_p,
                           const float* __restrict__ b0,
                           const float* __restrict__ bh,
                           const float* __restrict__ bL,
                           const unsigned short* __restrict__ ws,
                           float* __restrict__ out) {
  __shared__ __align__(16) char Hs[32 * 256];   // exactly 8 KB
  const int lane = threadIdx.x;
  const int lm = lane & 15, lh = lane >> 4;
  const int row0 = blockIdx.x * 32;
  const char* ap = reinterpret_cast<const char*>(ws) + lane * 16;
  const int xorm = (lm & 7) << 4;
  // LDS addr bases; rd(pt,ks) = va[pt] ^ (ks<<6), wr(nt,pt) = wa[pt] ^ (nt<<5)
  const int va0 = lm * 256 + ((lh * 16) ^ xorm);
  const int va1 = va0 + 16 * 256;
  const int wa0 = lm * 256 + ((lh * 8) ^ xorm);
  const int wa1 = wa0 + 16 * 256;

  // ---- issue L0 weight frags + L0 bias (C-in) loads up front ----
  bf16x8 aL0[8];
#pragma unroll
  for (int nt = 0; nt < 8; ++nt) aL0[nt] = GLD(ap + WS_WT0_B + nt * 1024);
  f32x4 bvh[8];   // rotating bias C-in set; starts as b0
#pragma unroll
  for (int nt = 0; nt < 8; ++nt)
    bvh[nt] = *reinterpret_cast<const f32x4*>(b0 + nt * 16 + lh * 4);

  // ---- stage scaled inputs (K padded to 32 -> 64B rows) ----
  if (lane < 32) {
    const float4 xv = reinterpret_cast<const float4*>(X)[row0 + lane];
    const float numin = nu_min_p[0], numax = nu_max_p[0];
    const float v0 = xv.x;
    const float v1 = xv.y;
    const float v2 = 2.f * xv.z - 1.f;
    const float v3 = 2.f * (xv.w - numin) / (numax - numin) - 1.f;
    uint4 c0;
    c0.x = (unsigned)f2b(v0) | ((unsigned)f2b(v1) << 16);
    c0.y = (unsigned)f2b(v2) | ((unsigned)f2b(v3) << 16);
    c0.z = 0u; c0.w = 0u;
    const uint4 z4 = make_uint4(0u, 0u, 0u, 0u);
    const int xr = (lane & 7) << 4;
    char* rp = Hs + lane * 256;
    *reinterpret_cast<uint4*>(rp + (0  ^ xr)) = c0;
    *reinterpret_cast<uint4*>(rp + (16 ^ xr)) = z4;
    *reinterpret_cast<uint4*>(rp + (32 ^ xr)) = z4;
    *reinterpret_cast<uint4*>(rp + (48 ^ xr)) = z4;
  }

  f32x4 acc[8][2];
  bf16x8 bfrA[2], bfrB[2];
  bf16x8 aA[8], aB[8];

  // ================= Layer 0 : K = 32, bias as MFMA C-in =================
  bfrA[0] = LRD(Hs + va0);
  bfrA[1] = LRD(Hs + va1);
#pragma unroll
  for (int nt = 0; nt < 8; ++nt) {
    acc[nt][0] = MFMA(aL0[nt], bfrA[0], bvh[nt]);
    acc[nt][1] = MFMA(aL0[nt], bfrA[1], bvh[nt]);
  }
  // bvh consumed -> prefetch bias for h=0; preload h=0 ks=0 weight frags
#pragma unroll
  for (int nt = 0; nt < 8; ++nt)
    bvh[nt] = *reinterpret_cast<const f32x4*>(bh + nt * 16 + lh * 4);
#pragma unroll
  for (int nt = 0; nt < 8; ++nt) aA[nt] = GLD(ap + WS_WTH_B + nt * 1024);
  // L0 epilogue (bias already in acc)
#pragma unroll
  for (int nt = 0; nt < 8; ++nt) {
#pragma unroll
    for (int pt = 0; pt < 2; ++pt) {
      const uint2 wv = pack4(swish4(acc[nt][pt]));
      *reinterpret_cast<uint2*>(Hs + ((pt ? wa1 : wa0) ^ (nt << 5))) = wv;
    }
  }

  // ============ 5 hidden layers : explicit 2-stage pipelined phases ============
#pragma unroll 1
  for (int h = 0; h < 5; ++h) {
    const char* wb = ap + WS_WTH_B + h * 32768;
    const float* bnext = bh + (h == 4 ? 4 : h + 1) * 128;

    // phase 0: compute ks0 with bias C-in; prefetch aB,bfrB <- ks1
    bfrA[0] = LRD(Hs + va0);
    bfrA[1] = LRD(Hs + va1);
#pragma unroll
    for (int nt = 0; nt < 8; ++nt) aB[nt] = GLD(wb + 8192 + nt * 1024);
    bfrB[0] = LRD(Hs + (va0 ^ 64));
    bfrB[1] = LRD(Hs + (va1 ^ 64));
#pragma unroll
    for (int nt = 0; nt < 8; ++nt) {
      acc[nt][0] = MFMA(aA[nt], bfrA[0], bvh[nt]);
      acc[nt][1] = MFMA(aA[nt], bfrA[1], bvh[nt]);
    }
    // bvh consumed -> prefetch next layer's bias (used ~3 phases later)
#pragma unroll
    for (int nt = 0; nt < 8; ++nt)
      bvh[nt] = *reinterpret_cast<const f32x4*>(bnext + nt * 16 + lh * 4);
    SB();
    // phase 1: compute ks1; prefetch aA,bfrA <- ks2
#pragma unroll
    for (int nt = 0; nt < 8; ++nt) aA[nt] = GLD(wb + 16384 + nt * 1024);
    bfrA[0] = LRD(Hs + (va0 ^ 128));
    bfrA[1] = LRD(Hs + (va1 ^ 128));
#pragma unroll
    for (int nt = 0; nt < 8; ++nt) {
      acc[nt][0] = MFMA(aB[nt], bfrB[0], acc[nt][0]);
      acc[nt][1] = MFMA(aB[nt], bfrB[1], acc[nt][1]);
    }
    SB();
    // phase 2: compute ks2; prefetch aB,bfrB <- ks3
#pragma unroll
    for (int nt = 0; nt < 8; ++nt) aB[nt] = GLD(wb + 24576 + nt * 1024);
    bfrB[0] = LRD(Hs + (va0 ^ 192));
    bfrB[1] = LRD(Hs + (va1 ^ 192));
#pragma unroll
    for (int nt = 0; nt < 8; ++nt) {
      acc[nt][0] = MFMA(aA[nt], bfrA[0], acc[nt][0]);
      acc[nt][1] = MFMA(aA[nt], bfrA[1], acc[nt][1]);
    }
    SB();
    // phase 3: compute ks3; prefetch aA <- next ks0 (continuous stream:
    // at h=4 this lands on WLT -> final-layer weights already in registers)
#pragma unroll
    for (int nt = 0; nt < 8; ++nt) aA[nt] = GLD(wb + 32768 + nt * 1024);
#pragma unroll
    for (int nt = 0; nt < 8; ++nt) {
      acc[nt][0] = MFMA(aB[nt], bfrB[0], acc[nt][0]);
      acc[nt][1] = MFMA(aB[nt], bfrB[1], acc[nt][1]);
    }
    SB();
    // epilogue: swish -> bf16 pack -> Hs (bias already in acc)
#pragma unroll
    for (int nt = 0; nt < 8; ++nt) {
#pragma unroll
      for (int pt = 0; pt < 2; ++pt) {
        const uint2 wv = pack4(swish4(acc[nt][pt]));
        *reinterpret_cast<uint2*>(Hs + ((pt ? wa1 : wa0) ^ (nt << 5))) = wv;
      }
    }
  }

  // ================= final layer : [128 -> 2], weights already in aA =================
  {
    const float bl0 = bL[0], bl1 = bL[1];
#pragma unroll
    for (int pt = 0; pt < 2; ++pt) {
      f32x4 accL = {0.f, 0.f, 0.f, 0.f};
#pragma unroll
      for (int ks = 0; ks < 4; ++ks) {
        const bf16x8 bfr = LRD(Hs + ((pt ? va1 : va0) ^ (ks << 6)));
        accL = MFMA(aA[ks], bfr, accL);
      }
      if (lh == 0) {
        const int p = pt * 16 + lm;
        float2 o;
        o.x = accL[0] + bl0;
        o.y = accL[1] + bl1;
        *reinterpret_cast<float2*>(out + (size_t)(row0 + p) * 2) = o;
      }
    }
  }
}

extern "C" void kernel_launch(void* const* d_in, const int* in_sizes, int n_in,
                              void* d_out, int out_size, void* d_ws, size_t ws_size,
                              hipStream_t stream) {
  const float* X     = (const float*)d_in[0];
  const float* numin = (const float*)d_in[1];
  const float* numax = (const float*)d_in[2];
  const float* W0    = (const float*)d_in[3];
  const float* b0    = (const float*)d_in[4];
  const float* Wh    = (const float*)d_in[5];
  const float* bh    = (const float*)d_in[6];
  const float* WL    = (const float*)d_in[7];
  const float* bL    = (const float*)d_in[8];
  unsigned short* ws = (unsigned short*)d_ws;
  float* out = (float*)d_out;

  hipLaunchKernelGGL(prep_kernel, dim3(352), dim3(256), 0, stream, W0, Wh, WL, ws);
  hipLaunchKernelGGL(mlp_kernel, dim3(8192), dim3(64), 0, stream,
                     X, numin, numax, b0, bh, bL, ws, out);
}

// Round 9
// 77.772 us; speedup vs baseline: 1.3711x; 1.3711x over previous
//
#include <hip/hip_runtime.h>

typedef __bf16 bf16x8 __attribute__((ext_vector_type(8)));
typedef __bf16 bf16x2 __attribute__((ext_vector_type(2)));
typedef float  f32x4  __attribute__((ext_vector_type(4)));

// ws layout (bytes). All A-operand fragments lane-linear:
// one frag = 1024 B; lane l's 16 B at frag_base + l*16 (coalesced dwordx4).
//   WT0 : 8 frags   (nt 0..7, K=32 zero-padded)      [0      .. 8191  ]
//   WTH : 160 frags ((h*4+ks)*8 + nt)                [8192   .. 172031]
//   WLT : 8 frags   (ks 0..3 real, 4..7 zero pad)    [172032 .. 180223]
#define WS_WT0_B 0
#define WS_WTH_B 8192
#define WS_WLT_B 172032

__device__ __forceinline__ unsigned short f2b(float f) {
  return __builtin_bit_cast(unsigned short, (__bf16)f);
}

__global__ void prep_kernel(const float* __restrict__ W0,
                            const float* __restrict__ Wh,
                            const float* __restrict__ WL,
                            unsigned short* __restrict__ ws) {
  int i = blockIdx.x * 256 + threadIdx.x;   // ushort index == byte/2
  int l  = (i >> 3) & 63;                   // lane within frag
  int j  = i & 7;                           // element within lane's 8
  int lm = l & 15, lh = l >> 4;
  if (i < 4096) {                           // WT0
    int nt = i >> 9;
    int n = nt * 16 + lm, k = lh * 8 + j;
    ws[i] = f2b(k < 4 ? W0[k * 128 + n] : 0.f);
  } else if (i < 86016) {                   // WTH
    int t = i - 4096;
    int frag = t >> 9;                      // (h*4+ks)*8 + nt
    int nt = frag & 7, ks = (frag >> 3) & 3, h = frag >> 5;
    int n = nt * 16 + lm, k = ks * 32 + lh * 8 + j;
    ws[i] = f2b(Wh[(h * 128 + k) * 128 + n]);
  } else if (i < 90112) {                   // WLT (8 frags, 4 real + 4 zero)
    int t = i - 86016;
    int f = t >> 9;
    int k = (f & 3) * 32 + lh * 8 + j;
    ws[i] = f2b((f < 4 && lm < 2) ? WL[k * 2 + lm] : 0.f);
  }
}

// swish via exp2: u = z * -log2(e) (v_pk_mul), e = 2^u, s = rcp(1+e), z*s.
__device__ __forceinline__ f32x4 swish4(f32x4 z) {
  const f32x4 u = z * (-1.44269504088896340736f);   // 2x v_pk_mul
  f32x4 e;
#if __has_builtin(__builtin_amdgcn_exp2f)
  e[0] = __builtin_amdgcn_exp2f(u[0]); e[1] = __builtin_amdgcn_exp2f(u[1]);
  e[2] = __builtin_amdgcn_exp2f(u[2]); e[3] = __builtin_amdgcn_exp2f(u[3]);
#else
  e[0] = __expf(u[0] * 0.6931471805599453f); e[1] = __expf(u[1] * 0.6931471805599453f);
  e[2] = __expf(u[2] * 0.6931471805599453f); e[3] = __expf(u[3] * 0.6931471805599453f);
#endif
  const f32x4 w = e + 1.f;                          // 2x v_pk_add
  f32x4 s;
  s[0] = __builtin_amdgcn_rcpf(w[0]); s[1] = __builtin_amdgcn_rcpf(w[1]);
  s[2] = __builtin_amdgcn_rcpf(w[2]); s[3] = __builtin_amdgcn_rcpf(w[3]);
  return z * s;                                     // 2x v_pk_mul
}

__device__ __forceinline__ uint2 pack4(f32x4 r) {   // v_cvt_pk_bf16_f32 path
  bf16x2 lo = {(__bf16)r[0], (__bf16)r[1]};
  bf16x2 hi = {(__bf16)r[2], (__bf16)r[3]};
  uint2 wv;
  wv.x = __builtin_bit_cast(unsigned int, lo);
  wv.y = __builtin_bit_cast(unsigned int, hi);
  return wv;
}

#define SB() __builtin_amdgcn_sched_barrier(0)
#define GLD(addr) __builtin_bit_cast(bf16x8, *reinterpret_cast<const uint4*>(addr))
#define LRD(addr) __builtin_bit_cast(bf16x8, *reinterpret_cast<const uint4*>(addr))
#define MFMA(a, b, c) __builtin_amdgcn_mfma_f32_16x16x32_bf16((a), (b), (c), 0, 0, 0)

// One wave per block; each wave owns 32 points through ALL layers. No barriers.
// 2-stage software pipeline on weight frags; sched_barrier(0) pins phases.
// Biases cached in LDS, consumed in the epilogue (short-lived registers —
// the R8 rotating bias-C-in set pushed the live set past the 3-wave cap and
// spilled; this layout fits: ~84 VGPR + 64 AGPR = 148 <= 170).
__launch_bounds__(64, 3)
__global__ void mlp_kernel(const float* __restrict__ X,
                           const float* __restrict__ nu_min_p,
                           const float* __restrict__ nu_max_p,
                           const float* __restrict__ b0,
                           const float* __restrict__ bh,
                           const float* __restrict__ bL,
                           const unsigned short* __restrict__ ws,
                           float* __restrict__ out) {
  __shared__ __align__(16) char smem[32 * 256 + 5 * 128 * 4];  // Hs + bh cache
  char* Hs = smem;
  float* bias_lds = reinterpret_cast<float*>(smem + 8192);
  const int lane = threadIdx.x;
  const int lm = lane & 15, lh = lane >> 4;
  const int row0 = blockIdx.x * 32;
  const char* ap = reinterpret_cast<const char*>(ws) + lane * 16;
  const int xorm = (lm & 7) << 4;
  // LDS addr bases; rd(pt,ks) = va[pt] ^ (ks<<6), wr(nt,pt) = wa[pt] ^ (nt<<5)
  const int va0 = lm * 256 + ((lh * 16) ^ xorm);
  const int va1 = va0 + 16 * 256;
  const int wa0 = lm * 256 + ((lh * 8) ^ xorm);
  const int wa1 = wa0 + 16 * 256;

  // ---- issue L0 weight frags + L0 bias (C-in) + bh staging loads up front ----
  bf16x8 aL0[8];
#pragma unroll
  for (int nt = 0; nt < 8; ++nt) aL0[nt] = GLD(ap + WS_WT0_B + nt * 1024);
  f32x4 bv0[8];
#pragma unroll
  for (int nt = 0; nt < 8; ++nt)
    bv0[nt] = *reinterpret_cast<const f32x4*>(b0 + nt * 16 + lh * 4);
  float bstg[10];
#pragma unroll
  for (int i = 0; i < 10; ++i) bstg[i] = bh[i * 64 + lane];

  // ---- stage scaled inputs (K padded to 32 -> 64B rows) ----
  if (lane < 32) {
    const float4 xv = reinterpret_cast<const float4*>(X)[row0 + lane];
    const float numin = nu_min_p[0], numax = nu_max_p[0];
    const float v0 = xv.x;
    const float v1 = xv.y;
    const float v2 = 2.f * xv.z - 1.f;
    const float v3 = 2.f * (xv.w - numin) / (numax - numin) - 1.f;
    uint4 c0;
    c0.x = (unsigned)f2b(v0) | ((unsigned)f2b(v1) << 16);
    c0.y = (unsigned)f2b(v2) | ((unsigned)f2b(v3) << 16);
    c0.z = 0u; c0.w = 0u;
    const uint4 z4 = make_uint4(0u, 0u, 0u, 0u);
    const int xr = (lane & 7) << 4;
    char* rp = Hs + lane * 256;
    *reinterpret_cast<uint4*>(rp + (0  ^ xr)) = c0;
    *reinterpret_cast<uint4*>(rp + (16 ^ xr)) = z4;
    *reinterpret_cast<uint4*>(rp + (32 ^ xr)) = z4;
    *reinterpret_cast<uint4*>(rp + (48 ^ xr)) = z4;
  }
  // bh -> LDS (consumed by hidden-layer epilogues)
#pragma unroll
  for (int i = 0; i < 10; ++i) bias_lds[i * 64 + lane] = bstg[i];

  f32x4 acc[8][2];
  bf16x8 bfrA[2], bfrB[2];
  bf16x8 aA[8], aB[8];

  // ================= Layer 0 : K = 32, bias as MFMA C-in =================
  bfrA[0] = LRD(Hs + va0);
  bfrA[1] = LRD(Hs + va1);
#pragma unroll
  for (int nt = 0; nt < 8; ++nt) {
    acc[nt][0] = MFMA(aL0[nt], bfrA[0], bv0[nt]);
    acc[nt][1] = MFMA(aL0[nt], bfrA[1], bv0[nt]);
  }
  // preload h=0 ks=0 weight frags (hidden under L0 epilogue)
#pragma unroll
  for (int nt = 0; nt < 8; ++nt) aA[nt] = GLD(ap + WS_WTH_B + nt * 1024);
  // L0 epilogue (bias already in acc)
#pragma unroll
  for (int nt = 0; nt < 8; ++nt) {
#pragma unroll
    for (int pt = 0; pt < 2; ++pt) {
      const uint2 wv = pack4(swish4(acc[nt][pt]));
      *reinterpret_cast<uint2*>(Hs + ((pt ? wa1 : wa0) ^ (nt << 5))) = wv;
    }
  }

  const f32x4 zero4 = {0.f, 0.f, 0.f, 0.f};

  // ============ 5 hidden layers : explicit 2-stage pipelined phases ============
#pragma unroll 1
  for (int h = 0; h < 5; ++h) {
    const char* wb = ap + WS_WTH_B + h * 32768;
    const float* bl = bias_lds + h * 128;

    // phase 0: compute with aA/bfrA(ks0); prefetch aB,bfrB <- ks1
    bfrA[0] = LRD(Hs + va0);
    bfrA[1] = LRD(Hs + va1);
#pragma unroll
    for (int nt = 0; nt < 8; ++nt) aB[nt] = GLD(wb + 8192 + nt * 1024);
    bfrB[0] = LRD(Hs + (va0 ^ 64));
    bfrB[1] = LRD(Hs + (va1 ^ 64));
#pragma unroll
    for (int nt = 0; nt < 8; ++nt) {
      acc[nt][0] = MFMA(aA[nt], bfrA[0], zero4);
      acc[nt][1] = MFMA(aA[nt], bfrA[1], zero4);
    }
    SB();
    // phase 1: compute with aB/bfrB(ks1); prefetch aA,bfrA <- ks2
#pragma unroll
    for (int nt = 0; nt < 8; ++nt) aA[nt] = GLD(wb + 16384 + nt * 1024);
    bfrA[0] = LRD(Hs + (va0 ^ 128));
    bfrA[1] = LRD(Hs + (va1 ^ 128));
#pragma unroll
    for (int nt = 0; nt < 8; ++nt) {
      acc[nt][0] = MFMA(aB[nt], bfrB[0], acc[nt][0]);
      acc[nt][1] = MFMA(aB[nt], bfrB[1], acc[nt][1]);
    }
    SB();
    // phase 2: compute with aA/bfrA(ks2); prefetch aB,bfrB <- ks3
#pragma unroll
    for (int nt = 0; nt < 8; ++nt) aB[nt] = GLD(wb + 24576 + nt * 1024);
    bfrB[0] = LRD(Hs + (va0 ^ 192));
    bfrB[1] = LRD(Hs + (va1 ^ 192));
#pragma unroll
    for (int nt = 0; nt < 8; ++nt) {
      acc[nt][0] = MFMA(aA[nt], bfrA[0], acc[nt][0]);
      acc[nt][1] = MFMA(aA[nt], bfrA[1], acc[nt][1]);
    }
    SB();
    // phase 3: compute with aB/bfrB(ks3); prefetch aA <- next ks0 (continuous
    // stream: at h=4 this lands on WLT -> final-layer weights in registers)
#pragma unroll
    for (int nt = 0; nt < 8; ++nt) aA[nt] = GLD(wb + 32768 + nt * 1024);
#pragma unroll
    for (int nt = 0; nt < 8; ++nt) {
      acc[nt][0] = MFMA(aB[nt], bfrB[0], acc[nt][0]);
      acc[nt][1] = MFMA(aB[nt], bfrB[1], acc[nt][1]);
    }
    SB();
    // epilogue: bias (LDS) + swish -> bf16 pack -> Hs (in place)
#pragma unroll
    for (int nt = 0; nt < 8; ++nt) {
      const f32x4 bv = *reinterpret_cast<const f32x4*>(bl + nt * 16 + lh * 4);
#pragma unroll
      for (int pt = 0; pt < 2; ++pt) {
        const uint2 wv = pack4(swish4(acc[nt][pt] + bv));
        *reinterpret_cast<uint2*>(Hs + ((pt ? wa1 : wa0) ^ (nt << 5))) = wv;
      }
    }
  }

  // ================= final layer : [128 -> 2], weights already in aA =================
  {
    const float bl0 = bL[0], bl1 = bL[1];
#pragma unroll
    for (int pt = 0; pt < 2; ++pt) {
      f32x4 accL = {0.f, 0.f, 0.f, 0.f};
#pragma unroll
      for (int ks = 0; ks < 4; ++ks) {
        const bf16x8 bfr = LRD(Hs + ((pt ? va1 : va0) ^ (ks << 6)));
        accL = MFMA(aA[ks], bfr, accL);
      }
      if (lh == 0) {
        const int p = pt * 16 + lm;
        float2 o;
        o.x = accL[0] + bl0;
        o.y = accL[1] + bl1;
        *reinterpret_cast<float2*>(out + (size_t)(row0 + p) * 2) = o;
      }
    }
  }
}

extern "C" void kernel_launch(void* const* d_in, const int* in_sizes, int n_in,
                              void* d_out, int out_size, void* d_ws, size_t ws_size,
                              hipStream_t stream) {
  const float* X     = (const float*)d_in[0];
  const float* numin = (const float*)d_in[1];
  const float* numax = (const float*)d_in[2];
  const float* W0    = (const float*)d_in[3];
  const float* b0    = (const float*)d_in[4];
  const float* bh    = (const float*)d_in[5 + 1];
  const float* Wh    = (const float*)d_in[5];
  const float* WL    = (const float*)d_in[7];
  const float* bL    = (const float*)d_in[8];
  unsigned short* ws = (unsigned short*)d_ws;
  float* out = (float*)d_out;

  hipLaunchKernelGGL(prep_kernel, dim3(352), dim3(256), 0, stream, W0, Wh, WL, ws);
  hipLaunchKernelGGL(mlp_kernel, dim3(8192), dim3(64), 0, stream,
                     X, numin, numax, b0, bh, bL, ws, out);
}

// Round 10
// 76.692 us; speedup vs baseline: 1.3904x; 1.0141x over previous
//
#include <hip/hip_runtime.h>

typedef __bf16 bf16x8 __attribute__((ext_vector_type(8)));
typedef __bf16 bf16x2 __attribute__((ext_vector_type(2)));
typedef float  f32x4  __attribute__((ext_vector_type(4)));

// ws layout (bytes). All A-operand fragments lane-linear:
// one frag = 1024 B; lane l's 16 B at frag_base + l*16 (coalesced dwordx4).
//   WT0 : 8 frags   (nt 0..7, K=32 zero-padded)      [0      .. 8191  ]
//   WTH : 160 frags ((h*4+ks)*8 + nt)                [8192   .. 172031]
//   WLT : 8 frags   (ks 0..3 real, 4..7 zero pad)    [172032 .. 180223]
#define WS_WT0_B 0
#define WS_WTH_B 8192
#define WS_WLT_B 172032

__device__ __forceinline__ unsigned short f2b(float f) {
  return __builtin_bit_cast(unsigned short, (__bf16)f);
}

__global__ void prep_kernel(const float* __restrict__ W0,
                            const float* __restrict__ Wh,
                            const float* __restrict__ WL,
                            unsigned short* __restrict__ ws) {
  int i = blockIdx.x * 256 + threadIdx.x;   // ushort index == byte/2
  int l  = (i >> 3) & 63;                   // lane within frag
  int j  = i & 7;                           // element within lane's 8
  int lm = l & 15, lh = l >> 4;
  if (i < 4096) {                           // WT0
    int nt = i >> 9;
    int n = nt * 16 + lm, k = lh * 8 + j;
    ws[i] = f2b(k < 4 ? W0[k * 128 + n] : 0.f);
  } else if (i < 86016) {                   // WTH
    int t = i - 4096;
    int frag = t >> 9;                      // (h*4+ks)*8 + nt
    int nt = frag & 7, ks = (frag >> 3) & 3, h = frag >> 5;
    int n = nt * 16 + lm, k = ks * 32 + lh * 8 + j;
    ws[i] = f2b(Wh[(h * 128 + k) * 128 + n]);
  } else if (i < 90112) {                   // WLT (8 frags, 4 real + 4 zero)
    int t = i - 86016;
    int f = t >> 9;
    int k = (f & 3) * 32 + lh * 8 + j;
    ws[i] = f2b((f < 4 && lm < 2) ? WL[k * 2 + lm] : 0.f);
  }
}

// swish via exp2: u = z * -log2(e), e = 2^u, s = rcp(1+e), z*s.
__device__ __forceinline__ f32x4 swish4(f32x4 z) {
  const f32x4 u = z * (-1.44269504088896340736f);
  f32x4 e;
#if __has_builtin(__builtin_amdgcn_exp2f)
  e[0] = __builtin_amdgcn_exp2f(u[0]); e[1] = __builtin_amdgcn_exp2f(u[1]);
  e[2] = __builtin_amdgcn_exp2f(u[2]); e[3] = __builtin_amdgcn_exp2f(u[3]);
#else
  e[0] = __expf(u[0] * 0.6931471805599453f); e[1] = __expf(u[1] * 0.6931471805599453f);
  e[2] = __expf(u[2] * 0.6931471805599453f); e[3] = __expf(u[3] * 0.6931471805599453f);
#endif
  const f32x4 w = e + 1.f;
  f32x4 s;
  s[0] = __builtin_amdgcn_rcpf(w[0]); s[1] = __builtin_amdgcn_rcpf(w[1]);
  s[2] = __builtin_amdgcn_rcpf(w[2]); s[3] = __builtin_amdgcn_rcpf(w[3]);
  return z * s;
}

__device__ __forceinline__ uint2 pack4(f32x4 r) {   // v_cvt_pk_bf16_f32 path
  bf16x2 lo = {(__bf16)r[0], (__bf16)r[1]};
  bf16x2 hi = {(__bf16)r[2], (__bf16)r[3]};
  uint2 wv;
  wv.x = __builtin_bit_cast(unsigned int, lo);
  wv.y = __builtin_bit_cast(unsigned int, hi);
  return wv;
}

#define LRD(addr) __builtin_bit_cast(bf16x8, *reinterpret_cast<const uint4*>(addr))
#define MFMA(a, b, c) __builtin_amdgcn_mfma_f32_16x16x32_bf16((a), (b), (c), 0, 0, 0)

// Cooperative 8KB stage: 256 threads x 2 x 16B direct global->LDS.
// LDS dest must be linear per wave (base + lane*16) -> our frag layout is.
__device__ __forceinline__ void stage8k(const char* src, char* dst, int tid) {
  const int woff = (tid >> 6) * 1024;    // wave-uniform LDS base
#if __has_builtin(__builtin_amdgcn_global_load_lds)
  __builtin_amdgcn_global_load_lds(
      (const __attribute__((address_space(1))) unsigned int*)(src + tid * 16),
      (__attribute__((address_space(3))) unsigned int*)(dst + woff), 16, 0, 0);
  __builtin_amdgcn_global_load_lds(
      (const __attribute__((address_space(1))) unsigned int*)(src + 4096 + tid * 16),
      (__attribute__((address_space(3))) unsigned int*)(dst + 4096 + woff), 16, 0, 0);
#else
  const uint4 v0 = *reinterpret_cast<const uint4*>(src + tid * 16);
  const uint4 v1 = *reinterpret_cast<const uint4*>(src + 4096 + tid * 16);
  *reinterpret_cast<uint4*>(dst + tid * 16) = v0;
  *reinterpret_cast<uint4*>(dst + 4096 + tid * 16) = v1;
#endif
}

// 4 waves/block. Each wave owns 32 points privately (Hs strip, epilogue,
// B-frags); the weight stream is SHARED: staged cooperatively into LDS,
// double-buffered at ks (8KB) granularity, one phase of prefetch ahead.
// Phase = { issue stage(next) ; ds_read A-frags(cur) ; 16 MFMA ;
//           [epilogue at layer end] ; __syncthreads }.
__launch_bounds__(256, 3)
__global__ void mlp_kernel(const float* __restrict__ X,
                           const float* __restrict__ nu_min_p,
                           const float* __restrict__ nu_max_p,
                           const float* __restrict__ b0,
                           const float* __restrict__ bh,
                           const float* __restrict__ bL,
                           const unsigned short* __restrict__ ws,
                           float* __restrict__ out) {
  __shared__ __align__(16) char smem[32768 + 16384 + 2560];
  const int tid  = threadIdx.x;
  const int lane = tid & 63, wave = tid >> 6;
  char* Hs  = smem + wave * 8192;          // private [32 pt][128 ch] strip
  char* wb0 = smem + 32768;                // shared weight buffers (8KB each)
  char* wb1 = smem + 40960;
  float* bias_lds = reinterpret_cast<float*>(smem + 49152);
  const int lm = lane & 15, lh = lane >> 4;
  const int row0 = blockIdx.x * 128 + wave * 32;
  const char* wsb = reinterpret_cast<const char*>(ws);
  const int xorm = (lm & 7) << 4;
  // rd(pt,ks) = va[pt] ^ (ks<<6); wr(nt,pt) = wa[pt] ^ (nt<<5)
  const int va0 = lm * 256 + ((lh * 16) ^ xorm);
  const int va1 = va0 + 4096;
  const int wa0 = lm * 256 + ((lh * 8) ^ xorm);
  const int wa1 = wa0 + 4096;

  // ---- prologue: stage L0 weights; bias cache; L0 bias regs; inputs ----
  stage8k(wsb + WS_WT0_B, wb0, tid);
  f32x4 bv0[8];
#pragma unroll
  for (int nt = 0; nt < 8; ++nt)
    bv0[nt] = *reinterpret_cast<const f32x4*>(b0 + nt * 16 + lh * 4);
#pragma unroll
  for (int i = 0; i < 3; ++i) {
    const int idx = i * 256 + tid;
    if (idx < 640) bias_lds[idx] = bh[idx];
  }
  if (lane < 32) {
    const float4 xv = reinterpret_cast<const float4*>(X)[row0 + lane];
    const float numin = nu_min_p[0], numax = nu_max_p[0];
    const float v0 = xv.x;
    const float v1 = xv.y;
    const float v2 = 2.f * xv.z - 1.f;
    const float v3 = 2.f * (xv.w - numin) / (numax - numin) - 1.f;
    uint4 c0;
    c0.x = (unsigned)f2b(v0) | ((unsigned)f2b(v1) << 16);
    c0.y = (unsigned)f2b(v2) | ((unsigned)f2b(v3) << 16);
    c0.z = 0u; c0.w = 0u;
    const uint4 z4 = make_uint4(0u, 0u, 0u, 0u);
    const int xr = (lane & 7) << 4;
    char* rp = Hs + lane * 256;
    *reinterpret_cast<uint4*>(rp + (0  ^ xr)) = c0;
    *reinterpret_cast<uint4*>(rp + (16 ^ xr)) = z4;
    *reinterpret_cast<uint4*>(rp + (32 ^ xr)) = z4;
    *reinterpret_cast<uint4*>(rp + (48 ^ xr)) = z4;
  }
  __syncthreads();

  f32x4 acc[8][2];
  bf16x8 aa[8];
  const f32x4 zero4 = {0.f, 0.f, 0.f, 0.f};

  // ---- L0 phase: read wb0 (K=32), stage h0/ks0 -> wb1, bias C-in ----
  stage8k(wsb + WS_WTH_B, wb1, tid);
#pragma unroll
  for (int nt = 0; nt < 8; ++nt) aa[nt] = LRD(wb0 + nt * 1024 + lane * 16);
  {
    const bf16x8 f0 = LRD(Hs + va0);
    const bf16x8 f1 = LRD(Hs + va1);
#pragma unroll
    for (int nt = 0; nt < 8; ++nt) {
      acc[nt][0] = MFMA(aa[nt], f0, bv0[nt]);
      acc[nt][1] = MFMA(aa[nt], f1, bv0[nt]);
    }
  }
#pragma unroll
  for (int nt = 0; nt < 8; ++nt) {
#pragma unroll
    for (int pt = 0; pt < 2; ++pt) {
      const uint2 wv = pack4(swish4(acc[nt][pt]));
      *reinterpret_cast<uint2*>(Hs + ((pt ? wa1 : wa0) ^ (nt << 5))) = wv;
    }
  }
  __syncthreads();

  // phase body: stage SRC -> SBUF, compute ks-slice from RBUF
#define HPHASE(RBUF, SBUF, SRC, KSOFF, FIRST)                              \
  do {                                                                     \
    stage8k((SRC), (SBUF), tid);                                           \
    _Pragma("unroll")                                                      \
    for (int nt = 0; nt < 8; ++nt) aa[nt] = LRD((RBUF) + nt * 1024 + lane * 16); \
    const bf16x8 f0 = LRD(Hs + (va0 ^ (KSOFF)));                           \
    const bf16x8 f1 = LRD(Hs + (va1 ^ (KSOFF)));                           \
    _Pragma("unroll")                                                      \
    for (int nt = 0; nt < 8; ++nt) {                                       \
      acc[nt][0] = MFMA(aa[nt], f0, (FIRST) ? zero4 : acc[nt][0]);         \
      acc[nt][1] = MFMA(aa[nt], f1, (FIRST) ? zero4 : acc[nt][1]);         \
    }                                                                      \
  } while (0)

  // ============ 5 hidden layers : 4 shared-stage phases each ============
#pragma unroll 1
  for (int h = 0; h < 5; ++h) {
    const char* wsrc = wsb + WS_WTH_B + h * 32768;
    const float* bl = bias_lds + h * 128;
    const char* nsrc = (h < 4) ? (wsrc + 32768) : (wsb + WS_WLT_B);

    HPHASE(wb1, wb0, wsrc + 8192,  0,   true);   // ks0 (stages ks1)
    __syncthreads();
    HPHASE(wb0, wb1, wsrc + 16384, 64,  false);  // ks1 (stages ks2)
    __syncthreads();
    HPHASE(wb1, wb0, wsrc + 24576, 128, false);  // ks2 (stages ks3)
    __syncthreads();
    HPHASE(wb0, wb1, nsrc,         192, false);  // ks3 (stages next/WLT)
    // epilogue before the barrier: covers the in-flight stage + absorbs skew
#pragma unroll
    for (int nt = 0; nt < 8; ++nt) {
      const f32x4 bv = *reinterpret_cast<const f32x4*>(bl + nt * 16 + lh * 4);
#pragma unroll
      for (int pt = 0; pt < 2; ++pt) {
        const uint2 wv = pack4(swish4(acc[nt][pt] + bv));
        *reinterpret_cast<uint2*>(Hs + ((pt ? wa1 : wa0) ^ (nt << 5))) = wv;
      }
    }
    __syncthreads();
  }

  // ================= final layer : [128 -> 2], weights in wb1 =================
  {
    const float bl0 = bL[0], bl1 = bL[1];
#pragma unroll
    for (int ks = 0; ks < 4; ++ks) aa[ks] = LRD(wb1 + ks * 1024 + lane * 16);
#pragma unroll
    for (int pt = 0; pt < 2; ++pt) {
      f32x4 accL = {0.f, 0.f, 0.f, 0.f};
#pragma unroll
      for (int ks = 0; ks < 4; ++ks) {
        const bf16x8 f = LRD(Hs + ((pt ? va1 : va0) ^ (ks << 6)));
        accL = MFMA(aa[ks], f, accL);
      }
      if (lh == 0) {
        const int p = pt * 16 + lm;
        float2 o;
        o.x = accL[0] + bl0;
        o.y = accL[1] + bl1;
        *reinterpret_cast<float2*>(out + (size_t)(row0 + p) * 2) = o;
      }
    }
  }
#undef HPHASE
}

extern "C" void kernel_launch(void* const* d_in, const int* in_sizes, int n_in,
                              void* d_out, int out_size, void* d_ws, size_t ws_size,
                              hipStream_t stream) {
  const float* X     = (const float*)d_in[0];
  const float* numin = (const float*)d_in[1];
  const float* numax = (const float*)d_in[2];
  const float* W0    = (const float*)d_in[3];
  const float* b0    = (const float*)d_in[4];
  const float* Wh    = (const float*)d_in[5];
  const float* bh    = (const float*)d_in[6];
  const float* WL    = (const float*)d_in[7];
  const float* bL    = (const float*)d_in[8];
  unsigned short* ws = (unsigned short*)d_ws;
  float* out = (float*)d_out;

  hipLaunchKernelGGL(prep_kernel, dim3(352), dim3(256), 0, stream, W0, Wh, WL, ws);
  hipLaunchKernelGGL(mlp_kernel, dim3(2048), dim3(256), 0, stream,
                     X, numin, numax, b0, bh, bL, ws, out);
}